// Round 2
// baseline (162.595 us; speedup 1.0000x reference)
//
#include <hip/hip_runtime.h>

// GnnLayer: out[50000,64] = leaky_relu((h[idx]/dist).reshape(N,2048) @ W + bias)
// R2 design: bf16 MFMA 16x16x32; 32 rows/wave (2 m-tiles x 4 n-tiles);
// A gathered+scaled directly from global (no LDS); B staged in BK=256 chunks
// (8 stages, 16 barriers) with VGPR prefetch; conflict-free padded LDS.
// ws: [0,256KB) W^T bf16 [64][2048]; [256KB,+6.4MB) h bf16 [50000][64]

#define N_NODES 50000
#define KN      32
#define FIN     64
#define FOUT    64
#define KDIM    2048
#define MROWS   128          // rows per block
#define BK      256          // K elems staged per stage
#define NSTAGE  (KDIM / BK)  // 8
#define SB_STRIDE 264        // 256 + 8 pad (elems) -> 528 B row stride
#define META_STRIDE 33

typedef __attribute__((ext_vector_type(4))) float f32x4;
typedef __attribute__((ext_vector_type(8))) short bf16x8;

static __device__ __forceinline__ unsigned short f2b(float f) {
    union { float f; unsigned int u; } v; v.f = f;
    unsigned int u = v.u;
    unsigned int r = (u + 0x7fffu + ((u >> 16) & 1u)) >> 16;  // RNE
    return (unsigned short)r;
}

// scale 8 bf16 by f32: unpack pairs, mul, round-half-up, perm-pack high halves
static __device__ __forceinline__ bf16x8 scale8(bf16x8 v, float scl) {
    union U { bf16x8 h; unsigned int u[4]; };
    U in, out; in.h = v;
#pragma unroll
    for (int i = 0; i < 4; ++i) {
        unsigned int p = in.u[i];
        float lo = __builtin_bit_cast(float, p << 16);
        float hi = __builtin_bit_cast(float, p & 0xffff0000u);
        unsigned int rlo = __builtin_bit_cast(unsigned int, lo * scl) + 0x8000u;
        unsigned int rhi = __builtin_bit_cast(unsigned int, hi * scl) + 0x8000u;
        out.u[i] = __builtin_amdgcn_perm(rhi, rlo, 0x07060302u);
    }
    return out.h;
}

// fused prep: h fp32 -> bf16 (3125 blocks) ; W[2048][64] -> W^T bf16 [64][2048]
__global__ void k_prep(const float* __restrict__ h, const float* __restrict__ w,
                       unsigned short* __restrict__ hb, unsigned short* __restrict__ wt) {
    int b = blockIdx.x, tid = threadIdx.x;
    if (b < (N_NODES * FIN / 4) / 256) {
        int i = b * 256 + tid;
        float4 v = ((const float4*)h)[i];
        ushort4 p;
        p.x = f2b(v.x); p.y = f2b(v.y); p.z = f2b(v.z); p.w = f2b(v.w);
        ((ushort4*)hb)[i] = p;
    } else {
        int i = (b - (N_NODES * FIN / 4) / 256) * 256 + tid;  // 0..131071
        int kidx = i >> 6, n = i & 63;
        wt[n * KDIM + kidx] = f2b(w[i]);
    }
}

__global__ __launch_bounds__(256) void k_main(
        const unsigned short* __restrict__ hb,   // bf16 h [N][64]
        const float*          __restrict__ pos,  // [N][3]
        const int*            __restrict__ nidx, // [N][32]
        const unsigned short* __restrict__ wt,   // bf16 W^T [64][2048]
        const float*          __restrict__ bias, // [64]
        float*                __restrict__ out)  // [N][64]
{
    __shared__ unsigned short sB[FOUT * SB_STRIDE];     // 33 KB B chunk
    __shared__ unsigned int   s_meta[MROWS * META_STRIDE]; // 16.9 KB idx|scl

    const int tid = threadIdx.x;
    const int m0  = blockIdx.x * MROWS;

    // Phase 0: pack (idx, bf16(1/dist)) per (row, kn). Stride-33 -> conflict-free.
    for (int p = tid; p < MROWS * KN; p += 256) {
        int row = p >> 5, kn = p & 31;
        int node = m0 + row;
        unsigned int pack = 0;
        if (node < N_NODES) {
            int idx = nidx[node * KN + kn];
            float dx = pos[node * 3 + 0] - pos[idx * 3 + 0];
            float dy = pos[node * 3 + 1] - pos[idx * 3 + 1];
            float dz = pos[node * 3 + 2] - pos[idx * 3 + 2];
            float sq = dx * dx + dy * dy + dz * dz;
            float scl = (sq == 0.f) ? 2.0f : __builtin_amdgcn_rsqf(sq);
            pack = (unsigned int)idx | ((unsigned int)f2b(scl) << 16);
        }
        s_meta[row * META_STRIDE + kn] = pack;
    }

    const int wv = tid >> 6, lane = tid & 63;
    const int lm = lane & 15, q = lane >> 4;
    const int rowbase = wv * 32;          // wave's rows: rowbase + mt*16 + lm
    const int sn = tid >> 2, sq4 = tid & 3;  // staging: 4 threads/row of sB

    f32x4 acc[2][4] = {};

    // prefetch B stage 0 into VGPRs
    const unsigned short* wrow = wt + sn * KDIM;
    bf16x8 pre[8];
#pragma unroll
    for (int r = 0; r < 8; ++r)
        pre[r] = *(const bf16x8*)(wrow + (sq4 * 8 + r) * 8);

    for (int s = 0; s < NSTAGE; ++s) {
        __syncthreads();   // prev-stage readers done (also covers s_meta @ s=0)
        {
            unsigned short* srow = sB + sn * SB_STRIDE;
#pragma unroll
            for (int r = 0; r < 8; ++r)
                *(bf16x8*)(srow + (sq4 * 8 + r) * 8) = pre[r];
        }
        __syncthreads();
        if (s + 1 < NSTAGE) {
#pragma unroll
            for (int r = 0; r < 8; ++r)
                pre[r] = *(const bf16x8*)(wrow + (s + 1) * BK + (sq4 * 8 + r) * 8);
        }
        const int kkbase = s * (BK / 32);
#pragma unroll
        for (int kk2 = 0; kk2 < BK / 32; ++kk2) {
            const int kk = kkbase + kk2;
            const int kn = kk >> 1, j0 = (kk & 1) * 32;
            bf16x8 a[2];
#pragma unroll
            for (int mt = 0; mt < 2; ++mt) {
                unsigned int meta = s_meta[(rowbase + mt * 16 + lm) * META_STRIDE + kn];
                float scl = __builtin_bit_cast(float, meta & 0xffff0000u);
                const unsigned short* ap = hb + (meta & 0xffffu) * FIN + j0 + q * 8;
                a[mt] = scale8(*(const bf16x8*)ap, scl);
            }
#pragma unroll
            for (int t = 0; t < 4; ++t) {
                bf16x8 b = *(const bf16x8*)(sB + (t * 16 + lm) * SB_STRIDE + kk2 * 32 + q * 8);
                acc[0][t] = __builtin_amdgcn_mfma_f32_16x16x32_bf16(a[0], b, acc[0][t], 0, 0, 0);
                acc[1][t] = __builtin_amdgcn_mfma_f32_16x16x32_bf16(a[1], b, acc[1][t], 0, 0, 0);
            }
        }
    }

    // Epilogue: bias + leaky_relu. C/D: col=lane&15, row=q*4+reg.
#pragma unroll
    for (int mt = 0; mt < 2; ++mt) {
#pragma unroll
        for (int t = 0; t < 4; ++t) {
            int f = t * 16 + lm;
            float bs = bias[f];
#pragma unroll
            for (int r = 0; r < 4; ++r) {
                int node = m0 + rowbase + mt * 16 + q * 4 + r;
                if (node < N_NODES) {
                    float v = acc[mt][t][r] + bs;
                    out[node * FOUT + f] = v > 0.f ? v : 0.01f * v;
                }
            }
        }
    }
}

extern "C" void kernel_launch(void* const* d_in, const int* in_sizes, int n_in,
                              void* d_out, int out_size, void* d_ws, size_t ws_size,
                              hipStream_t stream) {
    const float* h    = (const float*)d_in[0];
    const float* pos  = (const float*)d_in[1];
    const int*   nidx = (const int*)d_in[2];
    const float* w    = (const float*)d_in[3];
    const float* bias = (const float*)d_in[4];
    float* out = (float*)d_out;

    unsigned short* wt = (unsigned short*)d_ws;                    // 256 KB
    unsigned short* hb = (unsigned short*)((char*)d_ws + 262144);  // 6.4 MB

    int prep_blocks = (N_NODES * FIN / 4) / 256 + (KDIM * FOUT) / 256;  // 3125+512
    k_prep<<<prep_blocks, 256, 0, stream>>>(h, w, hb, wt);
    k_main<<<(N_NODES + MROWS - 1) / MROWS, 256, 0, stream>>>(hb, pos, nidx, wt, bias, out);
}